// Round 2
// baseline (189.052 us; speedup 1.0000x reference)
//
#include <hip/hip_runtime.h>
#include <hip/hip_bf16.h>
#include <math.h>

// NTXent loss, N=8192 rows, D=128.
// loss = mean_i [ log(sum_{j!=i} exp(2*cos_ij)) - 2*cos_{i,partner} ]
// Fused GEMM(8192x8192x128, bf16 MFMA) + exp + row-sum; sim never materialized.
// R1: 64 rows/wave (was 128) to kill register spill; 3-deep B prefetch.

typedef __attribute__((ext_vector_type(8))) short bf16x8;   // 8 bf16 = 4 VGPRs
typedef __attribute__((ext_vector_type(4))) float f32x4;

#define NROWS 8192
#define DDIM  128
#define BHALF 4096
// exp(2x) = 2^(x * 2/ln2)
#define EXP2SCALE 2.8853900817779268f

static __device__ __forceinline__ unsigned short f2bf(float f) {
  unsigned int u = __float_as_uint(f);
  unsigned int r = (u + 0x7fffu + ((u >> 16) & 1u)) >> 16;   // RNE
  return (unsigned short)r;
}

// ---- Kernel 1: row-normalize into bf16, zero row_sums and out ------------
__global__ void norm_zero_kernel(const float* __restrict__ zi, const float* __restrict__ zj,
                                 unsigned short* __restrict__ zn,
                                 float* __restrict__ row_sums, float* __restrict__ out) {
  int wave = threadIdx.x >> 6;
  int lane = threadIdx.x & 63;
  int row  = blockIdx.x * 4 + wave;                 // grid 2048 * 4 waves = 8192 rows
  const float* src = (row < BHALF) ? (zi + (size_t)row * DDIM)
                                   : (zj + (size_t)(row - BHALF) * DDIM);
  float2 v = *(const float2*)(src + 2 * lane);
  float ss = v.x * v.x + v.y * v.y;
  #pragma unroll
  for (int off = 1; off < 64; off <<= 1) ss += __shfl_xor(ss, off);
  float scale = 1.0f / fmaxf(sqrtf(ss), 1e-8f);
  unsigned int lo = f2bf(v.x * scale);
  unsigned int hi = f2bf(v.y * scale);
  ((unsigned int*)(zn + (size_t)row * DDIM))[lane] = lo | (hi << 16);

  if (threadIdx.x < 4) row_sums[blockIdx.x * 4 + threadIdx.x] = 0.0f;
  if (blockIdx.x == 0 && threadIdx.x == 0) out[0] = 0.0f;
}

// ---- Kernel 2: fused sim + exp + row-sum ---------------------------------
// Block = 4 waves. Wave owns 64 rows (a[4][4] = 64 VGPRs, loaded once).
// B frags streamed straight from global (zn is 2MB -> L2-resident), 3-deep
// rotating prefetch (2 tiles ahead ~ 310 cyc budget vs ~200 cyc L2 latency).
// Block tile: 256 rows x 256 cols. Grid (32,32) = 1024 blocks.
__global__ __launch_bounds__(256, 2)
void sim_kernel(const unsigned short* __restrict__ zn, float* __restrict__ row_sums) {
  const int wave = threadIdx.x >> 6;
  const int lane = threadIdx.x & 63;
  const int l15  = lane & 15;
  const int quad = lane >> 4;

  const int row_base = (blockIdx.x * 4 + wave) * 64;
  const int col_base = blockIdx.y * 256;

  // A fragments: A[m=l15][k=quad*8+j], 4 mi-tiles x 4 k-frags = 64 VGPRs
  bf16x8 a[4][4];
  const unsigned short* abase = zn + (size_t)(row_base + l15) * DDIM + quad * 8;
  #pragma unroll
  for (int mi = 0; mi < 4; ++mi)
    #pragma unroll
    for (int kf = 0; kf < 4; ++kf)
      a[mi][kf] = *(const bf16x8*)(abase + mi * 16 * DDIM + kf * 32);

  float rs[4][4];
  #pragma unroll
  for (int mi = 0; mi < 4; ++mi)
    #pragma unroll
    for (int r = 0; r < 4; ++r) rs[mi][r] = 0.0f;

  const unsigned short* bptr = zn + (size_t)(col_base + l15) * DDIM + quad * 8;
  bf16x8 b[3][4];                                   // rotating 3-deep prefetch
  #pragma unroll
  for (int kf = 0; kf < 4; ++kf) b[0][kf] = *(const bf16x8*)(bptr + kf * 32);
  #pragma unroll
  for (int kf = 0; kf < 4; ++kf) b[1][kf] = *(const bf16x8*)(bptr + 16 * DDIM + kf * 32);

  #pragma unroll
  for (int ni = 0; ni < 16; ++ni) {
    if (ni < 14) {                                  // prefetch tile ni+2
      const unsigned short* np = bptr + (size_t)(ni + 2) * 16 * DDIM;
      #pragma unroll
      for (int kf = 0; kf < 4; ++kf) b[(ni + 2) % 3][kf] = *(const bf16x8*)(np + kf * 32);
    }
    const int cur = ni % 3;
    f32x4 acc[4];
    #pragma unroll
    for (int mi = 0; mi < 4; ++mi) {
      f32x4 z = {0.0f, 0.0f, 0.0f, 0.0f};
      acc[mi] = __builtin_amdgcn_mfma_f32_16x16x32_bf16(a[mi][0], b[cur][0], z, 0, 0, 0);
    }
    #pragma unroll
    for (int kf = 1; kf < 4; ++kf)
      #pragma unroll
      for (int mi = 0; mi < 4; ++mi)
        acc[mi] = __builtin_amdgcn_mfma_f32_16x16x32_bf16(a[mi][kf], b[cur][kf], acc[mi], 0, 0, 0);
    // exp + accumulate (diagonal included; subtracted as exp(2) in finalize)
    #pragma unroll
    for (int mi = 0; mi < 4; ++mi)
      #pragma unroll
      for (int r = 0; r < 4; ++r)
        rs[mi][r] += __builtin_amdgcn_exp2f(acc[mi][r] * EXP2SCALE);
  }

  // C/D layout: col = l15, row = quad*4 + reg. Reduce the 16 cols per quad.
  #pragma unroll
  for (int mi = 0; mi < 4; ++mi)
    #pragma unroll
    for (int r = 0; r < 4; ++r) {
      float v = rs[mi][r];
      v += __shfl_xor(v, 1);
      v += __shfl_xor(v, 2);
      v += __shfl_xor(v, 4);
      v += __shfl_xor(v, 8);
      if (l15 == 0)
        atomicAdd(&row_sums[row_base + mi * 16 + quad * 4 + r], v);
    }
}

// ---- Kernel 3: positives + logs + mean -----------------------------------
__global__ void finalize_kernel(const unsigned short* __restrict__ zn,
                                const float* __restrict__ row_sums,
                                float* __restrict__ out) {
  int wave = threadIdx.x >> 6;
  int lane = threadIdx.x & 63;
  int i = blockIdx.x * 4 + wave;                   // grid 1024 * 4 = 4096 pairs
  int p = i + BHALF;
  unsigned int ua = ((const unsigned int*)(zn + (size_t)i * DDIM))[lane];
  unsigned int ub = ((const unsigned int*)(zn + (size_t)p * DDIM))[lane];
  float d = __uint_as_float(ua << 16) * __uint_as_float(ub << 16)
          + __uint_as_float(ua & 0xffff0000u) * __uint_as_float(ub & 0xffff0000u);
  #pragma unroll
  for (int off = 1; off < 64; off <<= 1) d += __shfl_xor(d, off);

  __shared__ float red[4];
  if (lane == 0) {
    const float EXPDIAG = 7.38905609893065f;       // exp(2): self-similarity term
    float si = row_sums[i] - EXPDIAG;
    float sp = row_sums[p] - EXPDIAG;
    red[wave] = logf(si) + logf(sp) - 4.0f * d;    // -pos_i - pos_p = -4*cos
  }
  __syncthreads();
  if (threadIdx.x == 0)
    atomicAdd(out, (red[0] + red[1] + red[2] + red[3]) * (1.0f / 8192.0f));
}

extern "C" void kernel_launch(void* const* d_in, const int* in_sizes, int n_in,
                              void* d_out, int out_size, void* d_ws, size_t ws_size,
                              hipStream_t stream) {
  const float* zi = (const float*)d_in[0];
  const float* zj = (const float*)d_in[1];
  unsigned short* zn = (unsigned short*)d_ws;                           // 8192*128 bf16 = 2 MB
  float* row_sums = (float*)((char*)d_ws + (size_t)NROWS * DDIM * 2);   // 8192 fp32
  float* out = (float*)d_out;

  norm_zero_kernel<<<2048, 256, 0, stream>>>(zi, zj, zn, row_sums, out);
  sim_kernel<<<dim3(32, 32), 256, 0, stream>>>(zn, row_sums);
  finalize_kernel<<<1024, 256, 0, stream>>>(zn, row_sums, out);
}

// Round 3
// 96.033 us; speedup vs baseline: 1.9686x; 1.9686x over previous
//
#include <hip/hip_runtime.h>
#include <hip/hip_bf16.h>
#include <math.h>

// NTXent loss, N=8192 rows, D=128.
// loss = mean_i [ log(sum_{j!=i} exp(2*cos_ij)) - 2*cos_{i,partner} ]
// R2: B tiles staged through double-buffered LDS via global_load_lds (no VGPR
// prefetch -> no spills, which killed R1: 302MB scratch writes, MfmaUtil 0.06%).
// A register-resident (64 rows/wave). XOR chunk swizzle kills LDS bank conflicts.

typedef __attribute__((ext_vector_type(8))) short bf16x8;   // 8 bf16 = 4 VGPRs
typedef __attribute__((ext_vector_type(4))) float f32x4;

#define NROWS 8192
#define DDIM  128
#define BHALF 4096
#define CHUNK 32                    // sim-cols per LDS chunk
#define COLS_PER_STRIP 512
// exp(2x) = 2^(x * 2/ln2)
#define EXP2SCALE 2.8853900817779268f

static __device__ __forceinline__ unsigned short f2bf(float f) {
  unsigned int u = __float_as_uint(f);
  unsigned int r = (u + 0x7fffu + ((u >> 16) & 1u)) >> 16;   // RNE
  return (unsigned short)r;
}

static __device__ __forceinline__ void glds16(const unsigned short* g, unsigned short* l) {
  // lane i writes LDS at (wave-uniform l) + lane*16B; per-lane global addr g.
  __builtin_amdgcn_global_load_lds((const __attribute__((address_space(1))) unsigned int*)g,
                                   (__attribute__((address_space(3))) unsigned int*)l,
                                   16, 0, 0);
}

// ---- Kernel 1: row-normalize into bf16, zero row_sums and out ------------
__global__ void norm_zero_kernel(const float* __restrict__ zi, const float* __restrict__ zj,
                                 unsigned short* __restrict__ zn,
                                 float* __restrict__ row_sums, float* __restrict__ out) {
  int wave = threadIdx.x >> 6;
  int lane = threadIdx.x & 63;
  int row  = blockIdx.x * 4 + wave;                 // grid 2048 * 4 waves = 8192 rows
  const float* src = (row < BHALF) ? (zi + (size_t)row * DDIM)
                                   : (zj + (size_t)(row - BHALF) * DDIM);
  float2 v = *(const float2*)(src + 2 * lane);
  float ss = v.x * v.x + v.y * v.y;
  #pragma unroll
  for (int off = 1; off < 64; off <<= 1) ss += __shfl_xor(ss, off);
  float scale = 1.0f / fmaxf(sqrtf(ss), 1e-8f);
  unsigned int lo = f2bf(v.x * scale);
  unsigned int hi = f2bf(v.y * scale);
  ((unsigned int*)(zn + (size_t)row * DDIM))[lane] = lo | (hi << 16);

  if (threadIdx.x < 4) row_sums[blockIdx.x * 4 + threadIdx.x] = 0.0f;
  if (blockIdx.x == 0 && threadIdx.x == 0) out[0] = 0.0f;
}

// ---- Kernel 2: fused sim + exp + row-sum ---------------------------------
// Block = 4 waves, tile 256 rows x 512 cols. Grid (32,16) = 512 blocks = 2/CU.
// A: a[4][4] = 64 VGPRs per wave, loaded once. B: 32-col chunks double-buffered
// in LDS via async global_load_lds (width 16). One barrier per chunk.
__global__ __launch_bounds__(256, 2)
void sim_kernel(const unsigned short* __restrict__ zn, float* __restrict__ row_sums) {
  __shared__ unsigned short lds[2 * CHUNK * DDIM];   // 2 x 8 KB

  const int wave = threadIdx.x >> 6;
  const int lane = threadIdx.x & 63;
  const int l15  = lane & 15;
  const int quad = lane >> 4;

  const int row_base  = blockIdx.x * 256 + wave * 64;
  const int col_strip = blockIdx.y * COLS_PER_STRIP;

  // A fragments: A[m=l15][k=quad*8+j]
  bf16x8 a[4][4];
  const unsigned short* abase = zn + (size_t)(row_base + l15) * DDIM + quad * 8;
  #pragma unroll
  for (int mi = 0; mi < 4; ++mi)
    #pragma unroll
    for (int kf = 0; kf < 4; ++kf)
      a[mi][kf] = *(const bf16x8*)(abase + mi * 16 * DDIM + kf * 32);

  float rs[4][4];
  #pragma unroll
  for (int mi = 0; mi < 4; ++mi)
    #pragma unroll
    for (int r = 0; r < 4; ++r) rs[mi][r] = 0.0f;

  // Staging geometry. LDS buffer = 32 rows x 16 chunks of 16B. Slot t holds
  // global chunk c = (t&15) ^ ((t>>4)&15) of B-row (t>>4)  [XOR swizzle].
  // Issue s in {0,1}: wave w covers slots t = s*256 + w*64 + lane.
  const int t0 = wave * 64 + lane;
  const int r0 = t0 >> 4, c0 = (t0 & 15) ^ (r0 & 15);
  const int r1 = (t0 + 256) >> 4, c1 = (t0 & 15) ^ (r1 & 15);
  const unsigned short* gst0 = zn + (size_t)(col_strip + r0) * DDIM + c0 * 8;
  const unsigned short* gst1 = zn + (size_t)(col_strip + r1) * DDIM + c1 * 8;
  unsigned short* lst0 = lds + wave * 512;           // + buf*4096 (elems)
  unsigned short* lst1 = lds + 2048 + wave * 512;

  // LDS read addresses (elements), per kf: row (ni*16 + l15), swizzled chunk
  // (quad + 4*kf) ^ l15. ni/buf enter as offsets.
  int rdoff[4];
  #pragma unroll
  for (int kf = 0; kf < 4; ++kf)
    rdoff[kf] = l15 * DDIM + (((quad + 4 * kf) ^ l15) << 3);

  // prime chunk 0 into buf 0
  glds16(gst0, lst0);
  glds16(gst1, lst1 - 2048 + 2048);                  // issue 1 of buf0: lds + 2048... 
  // (lst1 points at buf0 issue-1 window: lds + 2048 elems)
  __syncthreads();

  for (int ch = 0; ch < 16; ++ch) {
    const int buf = ch & 1;
    if (ch < 15) {                                   // stage chunk ch+1 -> other buf
      const unsigned short* g0 = gst0 + (size_t)(ch + 1) * CHUNK * DDIM;
      const unsigned short* g1 = gst1 + (size_t)(ch + 1) * CHUNK * DDIM;
      unsigned short* lb = lds + ((ch + 1) & 1) * 4096;
      glds16(g0, lb + wave * 512);
      glds16(g1, lb + 2048 + wave * 512);
    }
    const unsigned short* lb = lds + buf * 4096;
    #pragma unroll
    for (int ni = 0; ni < 2; ++ni) {
      bf16x8 b[4];
      #pragma unroll
      for (int kf = 0; kf < 4; ++kf)
        b[kf] = *(const bf16x8*)(lb + ni * 16 * DDIM + rdoff[kf]);
      f32x4 acc[4];
      #pragma unroll
      for (int mi = 0; mi < 4; ++mi) {
        f32x4 z = {0.0f, 0.0f, 0.0f, 0.0f};
        acc[mi] = __builtin_amdgcn_mfma_f32_16x16x32_bf16(a[mi][0], b[0], z, 0, 0, 0);
      }
      #pragma unroll
      for (int kf = 1; kf < 4; ++kf)
        #pragma unroll
        for (int mi = 0; mi < 4; ++mi)
          acc[mi] = __builtin_amdgcn_mfma_f32_16x16x32_bf16(a[mi][kf], b[kf], acc[mi], 0, 0, 0);
      // exp + accumulate (diagonal included; subtracted as exp(2) in finalize)
      #pragma unroll
      for (int mi = 0; mi < 4; ++mi)
        #pragma unroll
        for (int r = 0; r < 4; ++r)
          rs[mi][r] += __builtin_amdgcn_exp2f(acc[mi][r] * EXP2SCALE);
    }
    __syncthreads();                                 // drains glds (vmcnt) + compute
  }

  // C/D layout: col = l15, row = quad*4 + reg. Reduce the 16 cols per quad.
  #pragma unroll
  for (int mi = 0; mi < 4; ++mi)
    #pragma unroll
    for (int r = 0; r < 4; ++r) {
      float v = rs[mi][r];
      v += __shfl_xor(v, 1);
      v += __shfl_xor(v, 2);
      v += __shfl_xor(v, 4);
      v += __shfl_xor(v, 8);
      if (l15 == 0)
        atomicAdd(&row_sums[row_base + mi * 16 + quad * 4 + r], v);
    }
}

// ---- Kernel 3: positives + logs + mean -----------------------------------
__global__ void finalize_kernel(const unsigned short* __restrict__ zn,
                                const float* __restrict__ row_sums,
                                float* __restrict__ out) {
  int wave = threadIdx.x >> 6;
  int lane = threadIdx.x & 63;
  int i = blockIdx.x * 4 + wave;                   // grid 1024 * 4 = 4096 pairs
  int p = i + BHALF;
  unsigned int ua = ((const unsigned int*)(zn + (size_t)i * DDIM))[lane];
  unsigned int ub = ((const unsigned int*)(zn + (size_t)p * DDIM))[lane];
  float d = __uint_as_float(ua << 16) * __uint_as_float(ub << 16)
          + __uint_as_float(ua & 0xffff0000u) * __uint_as_float(ub & 0xffff0000u);
  #pragma unroll
  for (int off = 1; off < 64; off <<= 1) d += __shfl_xor(d, off);

  __shared__ float red[4];
  if (lane == 0) {
    const float EXPDIAG = 7.38905609893065f;       // exp(2): self-similarity term
    float si = row_sums[i] - EXPDIAG;
    float sp = row_sums[p] - EXPDIAG;
    red[wave] = logf(si) + logf(sp) - 4.0f * d;    // -pos_i - pos_p = -4*cos
  }
  __syncthreads();
  if (threadIdx.x == 0)
    atomicAdd(out, (red[0] + red[1] + red[2] + red[3]) * (1.0f / 8192.0f));
}

extern "C" void kernel_launch(void* const* d_in, const int* in_sizes, int n_in,
                              void* d_out, int out_size, void* d_ws, size_t ws_size,
                              hipStream_t stream) {
  const float* zi = (const float*)d_in[0];
  const float* zj = (const float*)d_in[1];
  unsigned short* zn = (unsigned short*)d_ws;                           // 8192*128 bf16 = 2 MB
  float* row_sums = (float*)((char*)d_ws + (size_t)NROWS * DDIM * 2);   // 8192 fp32
  float* out = (float*)d_out;

  norm_zero_kernel<<<2048, 256, 0, stream>>>(zi, zj, zn, row_sums, out);
  sim_kernel<<<dim3(32, 16), 256, 0, stream>>>(zn, row_sums);
  finalize_kernel<<<1024, 256, 0, stream>>>(zn, row_sums, out);
}